// Round 7
// baseline (811.903 us; speedup 1.0000x reference)
//
#include <hip/hip_runtime.h>
#include <math.h>

#define N_NODES 100000
#define N_EDGES 1600000
#define NB 64
#define F_IN 128
#define HDIM 64
#define NC 10
#define NBLK_NODES ((N_NODES + 255) / 256)

#define BSHIFT 9
#define BUCKET_NODES (1 << BSHIFT)                          // 512
#define NBUCK ((N_NODES + BUCKET_NODES - 1) >> BSHIFT)      // 196
#define EW_CHUNK 4096
#define EW_GRID ((N_EDGES + EW_CHUNK - 1) / EW_CHUNK)       // 391

// ---------- fused q/k/v/skip GEMM ----------
// 128x128 block tile (2 mats per pass, 2 passes over same X tile).
// Thread tile 8x8 in quad-split form: rows {tr*4..+3, 64+tr*4..+3},
// cols {tc*4..+3 (mat A), 64+tc*4..+3 (mat B)} -> all LDS b128 reads <=2-way.
// LDS: Xs[K][132] + Wt[16][132]: K=128 -> 76KB (2 blk/CU), K=64 -> 42KB (3 blk/CU).
template<int K>
__global__ __launch_bounds__(256) void qkvs_gemm_f(
    const float* __restrict__ xin,
    const float* __restrict__ Wq, const float* __restrict__ bq,
    const float* __restrict__ Wk, const float* __restrict__ bk,
    const float* __restrict__ Wv, const float* __restrict__ bv,
    const float* __restrict__ Ws, const float* __restrict__ bs,
    float* __restrict__ q, float* __restrict__ k,
    float* __restrict__ v, float* __restrict__ sk)
{
    __shared__ float Xs[K][132];   // transposed: Xs[k][row], row stride 132 (132%32=4)
    __shared__ float Wt[16][132];  // transposed: Wt[k][col], 2 mats x 64 cols

    const int tid  = threadIdx.x;
    const int row0 = blockIdx.x * 128;
    const int tc   = tid & 15;     // col quad within 64
    const int tr   = tid >> 4;     // row quad within 64

    // ---- stage X tile: 128 rows x K, transposed, float4 loads ----
    {
        const int r    = tid & 127;
        const int kh   = (tid >> 7) * 16;   // 0 or 16
        const int grow = row0 + r;
        for (int k0 = 0; k0 < K; k0 += 32) {
            float tmp[16];
            if (grow < N_NODES) {
                const float* p = xin + (size_t)grow * K + k0 + kh;
                float4 a = *(const float4*)p;
                float4 b = *(const float4*)(p + 4);
                float4 c = *(const float4*)(p + 8);
                float4 d = *(const float4*)(p + 12);
                tmp[0]=a.x; tmp[1]=a.y; tmp[2]=a.z; tmp[3]=a.w;
                tmp[4]=b.x; tmp[5]=b.y; tmp[6]=b.z; tmp[7]=b.w;
                tmp[8]=c.x; tmp[9]=c.y; tmp[10]=c.z; tmp[11]=c.w;
                tmp[12]=d.x; tmp[13]=d.y; tmp[14]=d.z; tmp[15]=d.w;
            } else {
                #pragma unroll
                for (int i = 0; i < 16; i++) tmp[i] = 0.f;
            }
            #pragma unroll
            for (int i = 0; i < 16; i++) Xs[k0 + kh + i][r] = tmp[i];
        }
    }

    const float* Wm[4] = {Wq, Wk, Wv, Ws};
    const float* Bm[4] = {bq, bk, bv, bs};
    float*       Om[4] = {q, k, v, sk};

    const int wcolsel = tid & 127;            // 0..127: which W col to stage
    const int wmatoff = wcolsel >> 6;         // 0/1 within pass
    const int wcol    = wcolsel & 63;
    const int wkh     = (tid >> 7) * 8;       // 0 or 8

    #pragma unroll
    for (int pass = 0; pass < 2; pass++) {
        float acc[2][2][4][4] = {};           // [rowhalf][mathalf][i][j]

        for (int k0 = 0; k0 < K; k0 += 16) {
            __syncthreads();                  // protect Wt (and Xs on first iter)
            {
                const float* pw = Wm[pass * 2 + wmatoff] + (size_t)wcol * K + k0 + wkh;
                float4 a = *(const float4*)pw;
                float4 b = *(const float4*)(pw + 4);
                float t8[8] = {a.x, a.y, a.z, a.w, b.x, b.y, b.z, b.w};
                #pragma unroll
                for (int i = 0; i < 8; i++) Wt[wkh + i][wcolsel] = t8[i];
            }
            __syncthreads();

            #pragma unroll
            for (int kk = 0; kk < 16; kk++) {
                float4 x0 = *(const float4*)&Xs[k0 + kk][tr * 4];
                float4 x1 = *(const float4*)&Xs[k0 + kk][64 + tr * 4];
                float4 w0 = *(const float4*)&Wt[kk][tc * 4];
                float4 w1 = *(const float4*)&Wt[kk][64 + tc * 4];
                float xa[2][4] = {{x0.x, x0.y, x0.z, x0.w}, {x1.x, x1.y, x1.z, x1.w}};
                float wa[2][4] = {{w0.x, w0.y, w0.z, w0.w}, {w1.x, w1.y, w1.z, w1.w}};
                #pragma unroll
                for (int rh = 0; rh < 2; rh++)
                    #pragma unroll
                    for (int ch = 0; ch < 2; ch++)
                        #pragma unroll
                        for (int i = 0; i < 4; i++)
                            #pragma unroll
                            for (int j = 0; j < 4; j++)
                                acc[rh][ch][i][j] += xa[rh][i] * wa[ch][j];
            }
        }

        #pragma unroll
        for (int ch = 0; ch < 2; ch++) {
            int mat = pass * 2 + ch;
            float4 bias = *(const float4*)&Bm[mat][tc * 4];
            float ba[4] = {bias.x, bias.y, bias.z, bias.w};
            float* out = Om[mat];
            #pragma unroll
            for (int rh = 0; rh < 2; rh++) {
                #pragma unroll
                for (int i = 0; i < 4; i++) {
                    int grow = row0 + rh * 64 + tr * 4 + i;
                    if (grow < N_NODES) {
                        float4 r;
                        r.x = acc[rh][ch][i][0] + ba[0];
                        r.y = acc[rh][ch][i][1] + ba[1];
                        r.z = acc[rh][ch][i][2] + ba[2];
                        r.w = acc[rh][ch][i][3] + ba[3];
                        *(float4*)&out[(size_t)grow * HDIM + tc * 4] = r;
                    }
                }
            }
        }
    }
}

// ---------- CSR build, stage 1: per-dst degree + per-bucket counts ----------
__global__ __launch_bounds__(256) void count_deg_bucket(
    const int* __restrict__ ei, int* __restrict__ deg, int* __restrict__ bcnt)
{
    __shared__ int hist[NBUCK];
    for (int i = threadIdx.x; i < NBUCK; i += 256) hist[i] = 0;
    __syncthreads();
    int e0 = blockIdx.x * EW_CHUNK;
    #pragma unroll
    for (int i = 0; i < EW_CHUNK / 256; i++) {
        int e = e0 + i * 256 + threadIdx.x;
        if (e < N_EDGES) {
            int dst = ei[N_EDGES + e];
            atomicAdd(&deg[dst], 1);
            atomicAdd(&hist[dst >> BSHIFT], 1);
        }
    }
    __syncthreads();
    for (int i = threadIdx.x; i < NBUCK; i += 256)
        if (hist[i]) atomicAdd(&bcnt[i], hist[i]);
}

// ---------- row_ptr scan (3 kernels) ----------
__global__ __launch_bounds__(256) void deg_block_sum(
    const int* __restrict__ deg, int* __restrict__ bsum)
{
    __shared__ int sh[256];
    int i = blockIdx.x * 256 + threadIdx.x;
    sh[threadIdx.x] = (i < N_NODES) ? deg[i] : 0;
    __syncthreads();
    #pragma unroll
    for (int off = 128; off; off >>= 1) {
        if (threadIdx.x < off) sh[threadIdx.x] += sh[threadIdx.x + off];
        __syncthreads();
    }
    if (threadIdx.x == 0) bsum[blockIdx.x] = sh[0];
}

__global__ __launch_bounds__(512) void scan_bsum(int* __restrict__ bsum, int nb)
{
    __shared__ int sh[512];
    int t = threadIdx.x;
    int v = (t < nb) ? bsum[t] : 0;
    sh[t] = v;
    __syncthreads();
    for (int off = 1; off < 512; off <<= 1) {
        int u = (t >= off) ? sh[t - off] : 0;
        __syncthreads();
        sh[t] += u;
        __syncthreads();
    }
    if (t < nb) bsum[t] = sh[t] - v;   // exclusive
}

__global__ __launch_bounds__(256) void write_rowptr(
    const int* __restrict__ deg, const int* __restrict__ bsum,
    int* __restrict__ row_ptr)
{
    __shared__ int sh[256];
    int i = blockIdx.x * 256 + threadIdx.x;
    int v = (i < N_NODES) ? deg[i] : 0;
    sh[threadIdx.x] = v;
    __syncthreads();
    for (int off = 1; off < 256; off <<= 1) {
        int u = (threadIdx.x >= off) ? sh[threadIdx.x - off] : 0;
        __syncthreads();
        sh[threadIdx.x] += u;
        __syncthreads();
    }
    if (i < N_NODES) {
        int ex = bsum[blockIdx.x] + sh[threadIdx.x] - v;
        row_ptr[i] = ex;
        if (i == N_NODES - 1) row_ptr[N_NODES] = bsum[blockIdx.x] + sh[threadIdx.x];
    }
}

// ---------- CSR build, stage 2: bucket base scan ----------
__global__ __launch_bounds__(256) void scan_bucket(
    const int* __restrict__ bcnt, int* __restrict__ bbase, int* __restrict__ gcursor)
{
    __shared__ int sh[256];
    int t = threadIdx.x;
    int v = (t < NBUCK) ? bcnt[t] : 0;
    sh[t] = v;
    __syncthreads();
    for (int off = 1; off < 256; off <<= 1) {
        int u = (t >= off) ? sh[t - off] : 0;
        __syncthreads();
        sh[t] += u;
        __syncthreads();
    }
    if (t < NBUCK) { bbase[t] = sh[t] - v; gcursor[t] = sh[t] - v; }
}

// ---------- CSR build, stage 3: scatter edges into bucket-ordered array ----------
__global__ __launch_bounds__(256) void bucket_scatter(
    const int* __restrict__ ei, int* __restrict__ gcursor, int2* __restrict__ bedge)
{
    __shared__ int hist[NBUCK];
    __shared__ int base[NBUCK];
    for (int i = threadIdx.x; i < NBUCK; i += 256) hist[i] = 0;
    __syncthreads();
    int e0 = blockIdx.x * EW_CHUNK;
    #pragma unroll
    for (int i = 0; i < EW_CHUNK / 256; i++) {
        int e = e0 + i * 256 + threadIdx.x;
        if (e < N_EDGES) atomicAdd(&hist[ei[N_EDGES + e] >> BSHIFT], 1);
    }
    __syncthreads();
    for (int i = threadIdx.x; i < NBUCK; i += 256)
        base[i] = hist[i] ? atomicAdd(&gcursor[i], hist[i]) : 0;
    __syncthreads();
    for (int i = threadIdx.x; i < NBUCK; i += 256) hist[i] = 0;
    __syncthreads();
    #pragma unroll
    for (int i = 0; i < EW_CHUNK / 256; i++) {
        int e = e0 + i * 256 + threadIdx.x;
        if (e < N_EDGES) {
            int src = ei[e];
            int dst = ei[N_EDGES + e];
            int b = dst >> BSHIFT;
            int pos = base[b] + atomicAdd(&hist[b], 1);
            bedge[pos] = make_int2(src, dst);
        }
    }
}

// ---------- CSR build, stage 4: one WG per bucket, LDS cursors ----------
__global__ __launch_bounds__(256) void csr_from_buckets(
    const int2* __restrict__ bedge, const int* __restrict__ bbase,
    const int* __restrict__ bcnt, const int* __restrict__ row_ptr,
    int* __restrict__ csr_src)
{
    __shared__ int cur[BUCKET_NODES];
    int b = blockIdx.x;
    int dst0 = b << BSHIFT;
    for (int i = threadIdx.x; i < BUCKET_NODES; i += 256) {
        int d = dst0 + i;
        cur[i] = (d < N_NODES) ? row_ptr[d] : 0;
    }
    __syncthreads();
    int beg = bbase[b], cnt = bcnt[b];
    for (int i = threadIdx.x; i < cnt; i += 256) {
        int2 ed = bedge[beg + i];
        int pos = atomicAdd(&cur[ed.y - dst0], 1);
        csr_src[pos] = ed.x;
    }
}

// ---------- fused attention: wave per dst, 4 edges/iter, float4 features ----------
__global__ __launch_bounds__(256) void attn_fused(
    const int* __restrict__ row_ptr, const int* __restrict__ csr_src,
    const float* __restrict__ q, const float* __restrict__ k,
    const float* __restrict__ v, const float* __restrict__ skip,
    float* __restrict__ hout, int do_relu)
{
    int n = blockIdx.x * 4 + (threadIdx.x >> 6);
    if (n >= N_NODES) return;
    int lane = threadIdx.x & 63;
    int g = lane >> 4;
    int t = lane & 15;
    int beg = row_ptr[n], end = row_ptr[n + 1];

    float4 qf = *(const float4*)&q[(size_t)n * HDIM + t * 4];
    float m = -1e30f, s = 0.f;
    float4 acc = make_float4(0.f, 0.f, 0.f, 0.f);

    for (int i = beg; i < end; i += 4) {
        int e = i + g;
        bool valid = (e < end);
        int src = csr_src[valid ? e : beg];
        float4 kf = *(const float4*)&k[(size_t)src * HDIM + t * 4];
        float4 vf = *(const float4*)&v[(size_t)src * HDIM + t * 4];
        float p = qf.x * kf.x + qf.y * kf.y + qf.z * kf.z + qf.w * kf.w;
        p += __shfl_xor(p, 1, 64);
        p += __shfl_xor(p, 2, 64);
        p += __shfl_xor(p, 4, 64);
        p += __shfl_xor(p, 8, 64);
        float a = valid ? p * 0.125f : -INFINITY;
        float mn = fmaxf(m, a);
        float sc = __expf(m - mn);
        float ew = __expf(a - mn);
        s = s * sc + ew;
        acc.x = acc.x * sc + ew * vf.x;
        acc.y = acc.y * sc + ew * vf.y;
        acc.z = acc.z * sc + ew * vf.z;
        acc.w = acc.w * sc + ew * vf.w;
        m = mn;
    }

    #pragma unroll
    for (int off = 16; off <= 32; off <<= 1) {
        float m2 = __shfl_xor(m, off, 64);
        float s2 = __shfl_xor(s, off, 64);
        float ax = __shfl_xor(acc.x, off, 64);
        float ay = __shfl_xor(acc.y, off, 64);
        float az = __shfl_xor(acc.z, off, 64);
        float aw = __shfl_xor(acc.w, off, 64);
        float mn = fmaxf(m, m2);
        float c1 = __expf(m - mn);
        float c2 = __expf(m2 - mn);
        s = s * c1 + s2 * c2;
        acc.x = acc.x * c1 + ax * c2;
        acc.y = acc.y * c1 + ay * c2;
        acc.z = acc.z * c1 + az * c2;
        acc.w = acc.w * c1 + aw * c2;
        m = mn;
    }

    if (g == 0) {
        float inv = (s > 0.f) ? (1.f / s) : 0.f;
        float4 sk4 = *(const float4*)&skip[(size_t)n * HDIM + t * 4];
        float4 val;
        val.x = acc.x * inv + sk4.x;
        val.y = acc.y * inv + sk4.y;
        val.z = acc.z * inv + sk4.z;
        val.w = acc.w * inv + sk4.w;
        if (do_relu) {
            val.x = fmaxf(val.x, 0.f);
            val.y = fmaxf(val.y, 0.f);
            val.z = fmaxf(val.z, 0.f);
            val.w = fmaxf(val.w, 0.f);
        }
        *(float4*)&hout[(size_t)n * HDIM + t * 4] = val;
    }
}

// ---------- mean pool: run-length accumulate (batch sorted) ----------
__global__ __launch_bounds__(256) void pool_kernel(
    const float* __restrict__ h, const int* __restrict__ batch,
    float* __restrict__ sums, float* __restrict__ cnt)
{
    int wid = blockIdx.x * 4 + (threadIdx.x >> 6);
    int n0 = wid * 64;
    if (n0 >= N_NODES) return;
    int lane = threadIdx.x & 63;
    int nend = min(n0 + 64, N_NODES);
    float acc = 0.f;
    int b_cur = batch[n0];
    int run = 0;
    for (int n = n0; n < nend; n++) {
        int b = batch[n];
        if (b != b_cur) {
            atomicAdd(&sums[b_cur * HDIM + lane], acc);
            if (lane == 0) atomicAdd(&cnt[b_cur], (float)run);
            acc = 0.f; run = 0; b_cur = b;
        }
        acc += h[(size_t)n * HDIM + lane];
        run++;
    }
    atomicAdd(&sums[b_cur * HDIM + lane], acc);
    if (lane == 0) atomicAdd(&cnt[b_cur], (float)run);
}

// ---------- head ----------
__global__ void head_kernel(
    const float* __restrict__ sums, const float* __restrict__ cnt,
    const float* __restrict__ Wl, const float* __restrict__ bl,
    float* __restrict__ out)
{
    int tid = threadIdx.x;
    if (tid >= NB * NC) return;
    int b = tid / NC, c = tid % NC;
    float cc = fmaxf(cnt[b], 1.0f);
    float acc = bl[c];
    #pragma unroll
    for (int f = 0; f < HDIM; f++)
        acc += (sums[b * HDIM + f] / cc) * Wl[c * HDIM + f];
    out[tid] = acc;
}

extern "C" void kernel_launch(void* const* d_in, const int* in_sizes, int n_in,
                              void* d_out, int out_size, void* d_ws, size_t ws_size,
                              hipStream_t stream)
{
    const float* x     = (const float*)d_in[0];
    const int*   ei    = (const int*)d_in[1];
    const int*   batch = (const int*)d_in[2];

    const float* W[3][4];
    const float* B[3][4];
    for (int l = 0; l < 3; l++)
        for (int j = 0; j < 4; j++) {
            W[l][j] = (const float*)d_in[3 + l * 8 + j * 2];
            B[l][j] = (const float*)d_in[3 + l * 8 + j * 2 + 1];
        }
    const float* Wl = (const float*)d_in[27];
    const float* bl = (const float*)d_in[28];
    float* out = (float*)d_out;

    const size_t NF = (size_t)N_NODES * HDIM;
    char* w = (char*)d_ws;
    float* h       = (float*)w;  w += NF * 4;
    float* q       = (float*)w;  w += NF * 4;
    float* kbuf    = (float*)w;  w += NF * 4;
    float* v       = (float*)w;  w += NF * 4;
    float* skip    = (float*)w;  w += NF * 4;
    int*   csr_src = (int*)w;    w += (size_t)N_EDGES * 4;
    int2*  bedge   = (int2*)w;   w += (size_t)N_EDGES * 8;
    int*   row_ptr = (int*)w;    w += (size_t)(N_NODES + 1) * 4;
    int*   deg     = (int*)w;    w += (size_t)N_NODES * 4;
    int*   bcnt    = (int*)w;    w += (size_t)NBUCK * 4;     // adjacent to deg: one memset
    int*   bbase   = (int*)w;    w += (size_t)NBUCK * 4;
    int*   gcursor = (int*)w;    w += (size_t)NBUCK * 4;
    int*   bsum    = (int*)w;    w += (size_t)NBLK_NODES * 4;
    float* sums    = (float*)w;  w += (size_t)NB * HDIM * 4;
    float* cnt     = (float*)w;  w += (size_t)NB * 4;

    const int gemm_gx = (N_NODES + 127) / 128;
    const int node_gx = (N_NODES + 3) / 4;
    const int pool_gx = (N_NODES + 64 * 4 - 1) / (64 * 4);

    // ----- CSR build via LDS-staged counting sort (once; shared by all layers) -----
    hipMemsetAsync(deg, 0, (size_t)(N_NODES + NBUCK) * 4, stream);   // deg + bcnt
    count_deg_bucket<<<EW_GRID, 256, 0, stream>>>(ei, deg, bcnt);
    deg_block_sum<<<NBLK_NODES, 256, 0, stream>>>(deg, bsum);
    scan_bsum<<<1, 512, 0, stream>>>(bsum, NBLK_NODES);
    write_rowptr<<<NBLK_NODES, 256, 0, stream>>>(deg, bsum, row_ptr);
    scan_bucket<<<1, 256, 0, stream>>>(bcnt, bbase, gcursor);
    bucket_scatter<<<EW_GRID, 256, 0, stream>>>(ei, gcursor, bedge);
    csr_from_buckets<<<NBUCK, 256, 0, stream>>>(bedge, bbase, bcnt, row_ptr, csr_src);

    for (int l = 0; l < 3; l++) {
        if (l == 0) {
            qkvs_gemm_f<F_IN><<<gemm_gx, 256, 0, stream>>>(
                x, W[0][0], B[0][0], W[0][1], B[0][1],
                   W[0][2], B[0][2], W[0][3], B[0][3], q, kbuf, v, skip);
        } else {
            qkvs_gemm_f<HDIM><<<gemm_gx, 256, 0, stream>>>(
                h, W[l][0], B[l][0], W[l][1], B[l][1],
                   W[l][2], B[l][2], W[l][3], B[l][3], q, kbuf, v, skip);
        }
        attn_fused<<<node_gx, 256, 0, stream>>>(
            row_ptr, csr_src, q, kbuf, v, skip, h, l < 2 ? 1 : 0);
    }

    hipMemsetAsync(sums, 0, (size_t)NB * HDIM * 4, stream);
    hipMemsetAsync(cnt,  0, (size_t)NB * 4, stream);
    pool_kernel<<<pool_gx, 256, 0, stream>>>(h, batch, sums, cnt);
    head_kernel<<<1, 640, 0, stream>>>(sums, cnt, Wl, bl, out);
}